// Round 13
// baseline (288.760 us; speedup 1.0000x reference)
//
#include <hip/hip_runtime.h>

#define SCALE 0.17677669529663687f

typedef __attribute__((ext_vector_type(8))) short bf16x8;
typedef __attribute__((ext_vector_type(4))) float f32x4;

__device__ __forceinline__ unsigned short f2bf(float f) {
    unsigned u = __float_as_uint(f);
    u += 0x7FFFu + ((u >> 16) & 1u);   // round-to-nearest-even
    return (unsigned short)(u >> 16);
}
__device__ __forceinline__ float bf2f(unsigned short s) {
    return __uint_as_float(((unsigned)s) << 16);
}
// pack two f32 -> u32 of 2 bf16 (lo = a, hi = b), RNE, pure C (NOTE: inline-asm
// v_cvt_pk_bf16_f32 produced NaNs in round 4 -- do not reintroduce without isolation)
__device__ __forceinline__ unsigned pk2c(float a, float b) {
    return (unsigned)f2bf(a) | ((unsigned)f2bf(b) << 16);
}

// ---------------- weights -> bf16 ----------------
__global__ __launch_bounds__(256) void wconv_kernel(
        const float* __restrict__ w_qkv, const float* __restrict__ w_out,
        unsigned short* __restrict__ wq, unsigned short* __restrict__ wo) {
    int idx = blockIdx.x * 256 + threadIdx.x;
    if (idx < 196608) wq[idx] = f2bf(w_qkv[idx]);
    else if (idx < 262144) wo[idx - 196608] = f2bf(w_out[idx - 196608]);
}

// ---- k1: fused QKV GEMM + MFMA head-attention. block = 32 consecutive tokens,
// 512 threads (8 waves), 64 KiB LDS, 2 blocks/CU, 3 barriers.
// GEMM (R12-proven): A = x-tile LDS, B = wq L2-stream, wave owns 96 of 768 ch.
// Bounce: q/k channels -> swizzled 16B-chunk layout; v channels -> vT[tok][d][g].
// Attention (NEW, MFMA): per wave 2 token-pairs;
//   QK:  S = mfma(Qfrag, Kfrag)  rows=(tok,h), cols=(tok',g), K=d=32
//   softmax: 8-lane xor-group shuffle reduce (groups never mix token-pairs)
//   P -> per-wave LDS buffer (16 rows x K=32, cross-token & pad slots = 0)
//   PV:  O = mfma(Pfrag, Vfrag) x2 (d-halves), V read from vT (16B contiguous)
//   O -> dead q-slot of each token (wave-local), coop-stored 1KB-contiguous.
// LDS: [0,16384) x-tile (dead after GEMM -> P-buffers, wave*1280, 80B row stride)
//      [16384,65536) per token t (1536B): [0,512) q chunks / later O[h][d];
//                    [512,1024) k chunks; [1024,1536) vT[d][g].
__global__ __launch_bounds__(512, 4) void qkv_attn_fused_kernel(
        const float* __restrict__ x, const unsigned short* __restrict__ wq,
        unsigned short* __restrict__ o_ws) {
    __shared__ unsigned char lds[65536];
    const int tid = threadIdx.x;
    const int tb  = blockIdx.x << 5;       // 32 consecutive tokens
    const int b   = tb >> 14;
    const float* xb = x + (size_t)b * 4194304 + (tb & 16383);

    // ---- stage x -> LDS bf16 [token][ch] swizzled (R11/R12-proven) ----
    {
        const int tok   = tid & 31;
        const int cbase = (tid >> 5) * 16;
        float f[16];
        #pragma unroll
        for (int e = 0; e < 16; ++e)
            f[e] = xb[(size_t)(cbase + e) * 16384 + tok];
        #pragma unroll
        for (int hlf = 0; hlf < 2; ++hlf) {
            const int c0 = cbase + hlf * 8;
            unsigned u0 = pk2c(f[hlf*8+0], f[hlf*8+1]), u1 = pk2c(f[hlf*8+2], f[hlf*8+3]);
            unsigned u2 = pk2c(f[hlf*8+4], f[hlf*8+5]), u3 = pk2c(f[hlf*8+6], f[hlf*8+7]);
            const int slot = (c0 >> 3) ^ (tok & 7);
            *(uint4*)(lds + tok * 512 + (slot << 4)) = make_uint4(u0, u1, u2, u3);
        }
    }
    __syncthreads();                       // barrier 1

    const int lane = tid & 63;
    const int wave = tid >> 6;
    const int lrow = lane & 15, lk = lane >> 4;
    const int j0w = wave * 96;

    // ---- single-k-loop GEMM over all 768 channels (R12-proven) ----
    f32x4 acc[2][6];
    #pragma unroll
    for (int mt = 0; mt < 2; ++mt)
        #pragma unroll
        for (int nt = 0; nt < 6; ++nt)
            acc[mt][nt] = (f32x4){0.f, 0.f, 0.f, 0.f};
    #pragma unroll
    for (int k = 0; k < 8; ++k) {
        bf16x8 a[2], bb[6];
        #pragma unroll
        for (int mt = 0; mt < 2; ++mt) {
            int t = mt * 16 + lrow;
            int slot = (k * 4 + lk) ^ (t & 7);
            a[mt] = *(const bf16x8*)(lds + t * 512 + (slot << 4));
        }
        #pragma unroll
        for (int nt = 0; nt < 6; ++nt) {
            int j = j0w + nt * 16 + lrow;
            bb[nt] = *(const bf16x8*)((const unsigned char*)wq + (size_t)j * 512 + k * 64 + lk * 16);
        }
        #pragma unroll
        for (int mt = 0; mt < 2; ++mt)
            #pragma unroll
            for (int nt = 0; nt < 6; ++nt)
                acc[mt][nt] = __builtin_amdgcn_mfma_f32_16x16x32_bf16(a[mt], bb[nt], acc[mt][nt], 0, 0, 0);
    }
    // ---- bounce: D[row=token][col=channel]; q/k -> chunk layout, v -> vT ----
    #pragma unroll
    for (int mt = 0; mt < 2; ++mt)
        #pragma unroll
        for (int nt = 0; nt < 6; ++nt) {
            const int chg = j0w + nt * 16;     // 16-ch group base (never crosses 512)
            #pragma unroll
            for (int i = 0; i < 4; ++i) {
                const int t = mt * 16 + lk * 4 + i;
                const int ch = chg + lrow;
                unsigned short v = f2bf(acc[mt][nt][i]);
                if (chg < 512) {
                    int c = ch >> 3, slot = c ^ (t & 7);
                    *(unsigned short*)(lds + 16384 + t * 1536 + (slot << 4) + (ch & 7) * 2) = v;
                } else {
                    int g = (ch - 512) >> 5, d = (ch - 512) & 31;
                    *(unsigned short*)(lds + 16384 + t * 1536 + 1024 + d * 16 + g * 2) = v;
                }
            }
        }
    __syncthreads();                       // barrier 2

    // ---- MFMA attention: wave owns tokens wave*4 .. wave*4+3 (2 pairs) ----
    {
        const int col   = lane & 15;
        const int chunk = lane >> 4;
        unsigned char* Pbuf = lds + wave * 1280;   // 16 rows x 80 B (K=32 bf16 + pad)
        const int tcol = (col >> 3);               // col-token within pair
        const int g    = col & 7;
        const int tloc = (chunk >> 1);             // row-token of this lane's 4 rows
        const bool valid = (tloc == tcol);

        #pragma unroll
        for (int p = 0; p < 2; ++p) {
            const int T0 = wave * 4 + p * 2;
            // Q/K fragments: row=(tok,h|g), k-chunk=(lane>>4)*8 d's -> one b128 each
            bf16x8 qf, kf;
            {
                const int trow = T0 + (col >> 3);
                const int hh = col & 7;
                const int cq = hh * 4 + chunk;
                qf = *(const bf16x8*)(lds + 16384 + trow * 1536 + (((cq) ^ (trow & 7)) << 4));
                const int ck = 32 + hh * 4 + chunk;
                kf = *(const bf16x8*)(lds + 16384 + trow * 1536 + (((ck) ^ (trow & 7)) << 4));
            }
            f32x4 s = __builtin_amdgcn_mfma_f32_16x16x32_bf16(qf, kf, (f32x4){0.f,0.f,0.f,0.f}, 0, 0, 0);
            // softmax over g: 8-lane xor-groups (same rows, same col-token)
            float pvls[4];
            #pragma unroll
            for (int i = 0; i < 4; ++i) {
                float si = s[i] * SCALE;
                float m = si;
                m = fmaxf(m, __shfl_xor(m, 1, 64));
                m = fmaxf(m, __shfl_xor(m, 2, 64));
                m = fmaxf(m, __shfl_xor(m, 4, 64));
                float e = __expf(si - m);
                float su = e;
                su += __shfl_xor(su, 1, 64);
                su += __shfl_xor(su, 2, 64);
                su += __shfl_xor(su, 4, 64);
                pvls[i] = e / su;
            }
            // P -> buffer: [row][k= tcol*16 + g], cross-token lanes write 0; pad k=+8..+15 zero
            #pragma unroll
            for (int i = 0; i < 4; ++i) {
                const int r = chunk * 4 + i;
                unsigned short pb = valid ? f2bf(pvls[i]) : (unsigned short)0;
                *(unsigned short*)(Pbuf + r * 80 + tcol * 32 + g * 2) = pb;
                *(unsigned short*)(Pbuf + r * 80 + tcol * 32 + 16 + g * 2) = 0;
            }
            // PV: A = P (row=(tok,h), k = 2tok x 16g-padded), B = vT (col=d, k contiguous g)
            bf16x8 pf = *(const bf16x8*)(Pbuf + col * 80 + chunk * 16);
            const int tv = T0 + (chunk >> 1);      // odd chunks read don't-care (P=0)
            bf16x8 vf0 = *(const bf16x8*)(lds + 16384 + tv * 1536 + 1024 + (col << 4));
            bf16x8 vf1 = *(const bf16x8*)(lds + 16384 + tv * 1536 + 1024 + ((16 + col) << 4));
            f32x4 o0 = __builtin_amdgcn_mfma_f32_16x16x32_bf16(pf, vf0, (f32x4){0.f,0.f,0.f,0.f}, 0, 0, 0);
            f32x4 o1 = __builtin_amdgcn_mfma_f32_16x16x32_bf16(pf, vf1, (f32x4){0.f,0.f,0.f,0.f}, 0, 0, 0);
            // O -> dead q-slot of token: [h][d] raw layout (wave-local region)
            #pragma unroll
            for (int i = 0; i < 4; ++i) {
                const int ro = chunk * 4 + i;
                const int tO = T0 + (ro >> 3);
                const int hO = ro & 7;
                *(unsigned short*)(lds + 16384 + tO * 1536 + hO * 64 + col * 2)        = f2bf(o0[i]);
                *(unsigned short*)(lds + 16384 + tO * 1536 + hO * 64 + (16 + col) * 2) = f2bf(o1[i]);
            }
        }
    }
    __syncthreads();                       // barrier 3

    // ---- coop store O -> o_ws (out2 layout), 1KB contiguous per wave instr ----
    {
        const int himg = (tb & 16383) >> 7;
        const int ih = himg >> 3, r = himg & 7;
        const int win0 = (b << 8) + (ih << 4) + ((tb & 127) >> 3);
        #pragma unroll
        for (int it = 0; it < 2; ++it) {
            const int q = it * 512 + tid;          // 16-B chunk id, 1024 total
            const int dchunk = q & 3;
            const int sloc   = (q >> 2) & 7;
            const int h      = (q >> 5) & 7;
            const int wloc   = q >> 8;
            bf16x8 v = *(const bf16x8*)(lds + 16384 + (size_t)(wloc * 8 + sloc) * 1536 + h * 64 + dchunk * 16);
            *(bf16x8*)(o_ws + (size_t)(win0 + wloc) * 16384 + (h * 8 + r) * 256 + sloc * 32 + dchunk * 8) = v;
        }
    }
}

// ---- k2: out-projection + bias + output scatter (32KB LDS, two y half-passes)
__global__ __launch_bounds__(512, 6) void outproj_kernel(
        const unsigned short* __restrict__ o_ws, const unsigned short* __restrict__ wo,
        const float* __restrict__ b_out, float* __restrict__ out) {
    __shared__ unsigned char lds[32768];
    const int tid = threadIdx.x;
    const int bid = blockIdx.x;
    const int b  = bid >> 8;
    const int ih = (bid >> 4) & 15;
    const int iw = bid & 15;

    {
        const unsigned char* src = (const unsigned char*)(o_ws + (size_t)bid * 16384);
        #pragma unroll
        for (int it = 0; it < 4; ++it) {
            int q = it * 512 + tid;            // 16-byte chunk id, 2048 total
            int np = q >> 5;                   // row n'
            int slot = (q & 31) ^ (np & 7);
            *(bf16x8*)(lds + np * 512 + (slot << 4)) = *(const bf16x8*)(src + q * 16);
        }
    }
    __syncthreads();

    const int lane = tid & 63;
    const int wave = tid >> 6;
    const int lrow = lane & 15;
    const int lk   = lane >> 4;
    const int j0 = wave * 32;

    f32x4 acc[4][2];
    #pragma unroll
    for (int mt = 0; mt < 4; ++mt)
        #pragma unroll
        for (int nt = 0; nt < 2; ++nt)
            acc[mt][nt] = (f32x4){0.f, 0.f, 0.f, 0.f};
    #pragma unroll
    for (int k = 0; k < 8; ++k) {
        bf16x8 a[4], bb[2];
        #pragma unroll
        for (int mt = 0; mt < 4; ++mt) {
            int t = mt * 16 + lrow;
            int slot = (k * 4 + lk) ^ (t & 7);
            a[mt] = *(const bf16x8*)(lds + t * 512 + (slot << 4));
        }
        #pragma unroll
        for (int nt = 0; nt < 2; ++nt) {
            int j = j0 + nt * 16 + lrow;
            bb[nt] = *(const bf16x8*)((const unsigned char*)wo + (size_t)j * 512 + k * 64 + lk * 16);
        }
        #pragma unroll
        for (int mt = 0; mt < 4; ++mt)
            #pragma unroll
            for (int nt = 0; nt < 2; ++nt)
                acc[mt][nt] = __builtin_amdgcn_mfma_f32_16x16x32_bf16(a[mt], bb[nt], acc[mt][nt], 0, 0, 0);
    }
    float bias[2];
    #pragma unroll
    for (int nt = 0; nt < 2; ++nt) bias[nt] = b_out[j0 + nt * 16 + lrow];
    __syncthreads();   // out2 tile dead; reuse LDS for fp32 y (two 128-col halves)

    const size_t obase = ((size_t)b * 256) * 16384 + (size_t)(iw * 8) * 128 + ih * 8;
    #pragma unroll
    for (int half = 0; half < 2; ++half) {
        if ((wave >> 2) == half) {
            int jl = (wave & 3) * 32;
            #pragma unroll
            for (int mt = 0; mt < 4; ++mt)
                #pragma unroll
                for (int nt = 0; nt < 2; ++nt)
                    #pragma unroll
                    for (int i = 0; i < 4; ++i) {
                        int t = mt * 16 + lk * 4 + i;
                        int el = jl + nt * 16 + lrow;      // 0..127
                        int sl = (el >> 2) ^ (t & 7);
                        *(float*)(lds + t * 512 + (sl << 4) + (el & 3) * 4) = acc[mt][nt][i] + bias[nt];
                    }
        }
        __syncthreads();
        #pragma unroll
        for (int it = 0; it < 2; ++it) {
            int idx = it * 512 + tid;              // 0..1023
            int el = idx >> 3, sp = idx & 7;       // el 0..127
            float vals[8];
            #pragma unroll
            for (int rp = 0; rp < 8; ++rp) {
                int t = rp * 8 + sp;
                int sl = (el >> 2) ^ (t & 7);
                vals[rp] = *(const float*)(lds + t * 512 + (sl << 4) + (el & 3) * 4);
            }
            float* po = out + obase + (size_t)(half * 128 + el) * 16384 + sp * 128;
            *(float4*)po       = make_float4(vals[0], vals[1], vals[2], vals[3]);
            *(float4*)(po + 4) = make_float4(vals[4], vals[5], vals[6], vals[7]);
        }
        __syncthreads();
    }
}

extern "C" void kernel_launch(void* const* d_in, const int* in_sizes, int n_in,
                              void* d_out, int out_size, void* d_ws, size_t ws_size,
                              hipStream_t stream) {
    const float* x     = (const float*)d_in[0];
    const float* w_qkv = (const float*)d_in[1];
    const float* w_out = (const float*)d_in[2];
    const float* b_out = (const float*)d_in[3];
    float* out = (float*)d_out;

    const size_t O_BYTES = 67108864;      // 2048 x 64 x 256 x 2

    unsigned short* o_ws = (unsigned short*)d_ws;
    unsigned short* wq   = (unsigned short*)((char*)d_ws + O_BYTES);
    unsigned short* wo   = wq + 196608;

    wconv_kernel<<<dim3(1024), dim3(256), 0, stream>>>(w_qkv, w_out, wq, wo);
    qkv_attn_fused_kernel<<<dim3(4096), dim3(512), 0, stream>>>(x, wq, o_ws);
    outproj_kernel<<<dim3(2048), dim3(512), 0, stream>>>(o_ws, wo, b_out, out);
}

// Round 14
// 287.413 us; speedup vs baseline: 1.0047x; 1.0047x over previous
//
#include <hip/hip_runtime.h>

#define SCALE 0.17677669529663687f

typedef __attribute__((ext_vector_type(8))) short bf16x8;
typedef __attribute__((ext_vector_type(4))) float f32x4;

__device__ __forceinline__ unsigned short f2bf(float f) {
    unsigned u = __float_as_uint(f);
    u += 0x7FFFu + ((u >> 16) & 1u);   // round-to-nearest-even
    return (unsigned short)(u >> 16);
}
__device__ __forceinline__ float bf2f(unsigned short s) {
    return __uint_as_float(((unsigned)s) << 16);
}
// pack two f32 -> u32 of 2 bf16 (lo = a, hi = b), RNE, pure C (NOTE: inline-asm
// v_cvt_pk_bf16_f32 produced NaNs in round 4 -- do not reintroduce without isolation)
__device__ __forceinline__ unsigned pk2c(float a, float b) {
    return (unsigned)f2bf(a) | ((unsigned)f2bf(b) << 16);
}

// ---------------- weights -> bf16 ----------------
__global__ __launch_bounds__(256) void wconv_kernel(
        const float* __restrict__ w_qkv, const float* __restrict__ w_out,
        unsigned short* __restrict__ wq, unsigned short* __restrict__ wo) {
    int idx = blockIdx.x * 256 + threadIdx.x;
    if (idx < 196608) wq[idx] = f2bf(w_qkv[idx]);
    else if (idx < 262144) wo[idx - 196608] = f2bf(w_out[idx - 196608]);
}

// ---- k1: fused QKV GEMM + head-attention (R12 structure, 228us proven).
// block = 32 consecutive tokens, 512 threads (8 waves), 64 KiB LDS, 2 blocks/CU,
// 2 barriers. Changes vs R12:
//  (1) B-map 2-way channel-interleaved (R10-proven): MFMA tile nt=2*pr+m holds
//      channel j0w + pr*32 + 2*lrow + m -> lane owns adjacent channel pairs ->
//      bounce = 24 ds_write_b32 + pk2c (was 48 ds_write_b16 + scalar f2bf).
//  (2) 2-deep double-buffered wq register pipeline (keeps L2 loads in flight).
//  (3) s_setprio(1) around MFMA clusters (2 resident blocks are phase-skewed).
// LDS: [0,16384) x-tile 32tok x 256ch bf16 swizzled (row 512 B);
//      [16384,65536) qkv 32tok x 768ch bf16 (row 1536 B, chunk-xor swizzle).
__global__ __launch_bounds__(512, 4) void qkv_attn_fused_kernel(
        const float* __restrict__ x, const unsigned short* __restrict__ wq,
        unsigned short* __restrict__ o_ws) {
    __shared__ unsigned char lds[65536];
    const int tid = threadIdx.x;
    const int tb  = blockIdx.x << 5;       // 32 consecutive tokens
    const int b   = tb >> 14;
    const float* xb = x + (size_t)b * 4194304 + (tb & 16383);

    // ---- stage x -> LDS bf16 [token][ch] swizzled (R11/R12-proven) ----
    {
        const int tok   = tid & 31;
        const int cbase = (tid >> 5) * 16;
        float f[16];
        #pragma unroll
        for (int e = 0; e < 16; ++e)
            f[e] = xb[(size_t)(cbase + e) * 16384 + tok];
        #pragma unroll
        for (int hlf = 0; hlf < 2; ++hlf) {
            const int c0 = cbase + hlf * 8;
            unsigned u0 = pk2c(f[hlf*8+0], f[hlf*8+1]), u1 = pk2c(f[hlf*8+2], f[hlf*8+3]);
            unsigned u2 = pk2c(f[hlf*8+4], f[hlf*8+5]), u3 = pk2c(f[hlf*8+6], f[hlf*8+7]);
            const int slot = (c0 >> 3) ^ (tok & 7);
            *(uint4*)(lds + tok * 512 + (slot << 4)) = make_uint4(u0, u1, u2, u3);
        }
    }
    __syncthreads();                       // barrier 1

    const int lane = tid & 63;
    const int wave = tid >> 6;
    const int lrow = lane & 15, lk = lane >> 4;
    const int j0w = wave * 96;

    // ---- single-k-loop GEMM over all 768 channels, 2-deep B pipeline ----
    f32x4 acc[2][6];
    #pragma unroll
    for (int mt = 0; mt < 2; ++mt)
        #pragma unroll
        for (int nt = 0; nt < 6; ++nt)
            acc[mt][nt] = (f32x4){0.f, 0.f, 0.f, 0.f};
    {
        const unsigned char* wqb = (const unsigned char*)wq;
        bf16x8 b0[6], b1[6];
        #pragma unroll
        for (int nt = 0; nt < 6; ++nt) {       // interleaved map: j = j0w+pr*32+2*lrow+m
            int j = j0w + (nt >> 1) * 32 + lrow * 2 + (nt & 1);
            b0[nt] = *(const bf16x8*)(wqb + (size_t)j * 512 + 0 * 64 + lk * 16);
        }
        #pragma unroll
        for (int k = 0; k < 8; k += 2) {
            #pragma unroll
            for (int nt = 0; nt < 6; ++nt) {
                int j = j0w + (nt >> 1) * 32 + lrow * 2 + (nt & 1);
                b1[nt] = *(const bf16x8*)(wqb + (size_t)j * 512 + (k + 1) * 64 + lk * 16);
            }
            {
                bf16x8 a[2];
                #pragma unroll
                for (int mt = 0; mt < 2; ++mt) {
                    int t = mt * 16 + lrow;
                    int slot = (k * 4 + lk) ^ (t & 7);
                    a[mt] = *(const bf16x8*)(lds + t * 512 + (slot << 4));
                }
                __builtin_amdgcn_s_setprio(1);
                #pragma unroll
                for (int mt = 0; mt < 2; ++mt)
                    #pragma unroll
                    for (int nt = 0; nt < 6; ++nt)
                        acc[mt][nt] = __builtin_amdgcn_mfma_f32_16x16x32_bf16(a[mt], b0[nt], acc[mt][nt], 0, 0, 0);
                __builtin_amdgcn_s_setprio(0);
            }
            if (k + 2 < 8) {
                #pragma unroll
                for (int nt = 0; nt < 6; ++nt) {
                    int j = j0w + (nt >> 1) * 32 + lrow * 2 + (nt & 1);
                    b0[nt] = *(const bf16x8*)(wqb + (size_t)j * 512 + (k + 2) * 64 + lk * 16);
                }
            }
            {
                bf16x8 a[2];
                #pragma unroll
                for (int mt = 0; mt < 2; ++mt) {
                    int t = mt * 16 + lrow;
                    int slot = ((k + 1) * 4 + lk) ^ (t & 7);
                    a[mt] = *(const bf16x8*)(lds + t * 512 + (slot << 4));
                }
                __builtin_amdgcn_s_setprio(1);
                #pragma unroll
                for (int mt = 0; mt < 2; ++mt)
                    #pragma unroll
                    for (int nt = 0; nt < 6; ++nt)
                        acc[mt][nt] = __builtin_amdgcn_mfma_f32_16x16x32_bf16(a[mt], b1[nt], acc[mt][nt], 0, 0, 0);
                __builtin_amdgcn_s_setprio(0);
            }
        }
    }
    // ---- bounce D-frags -> qkv LDS. Lane owns adjacent channel pairs ->
    //      paired b32 writes. row=lk*4+i -> token, pair base = j0w+pr*32+2*lrow ----
    #pragma unroll
    for (int mt = 0; mt < 2; ++mt)
        #pragma unroll
        for (int pr = 0; pr < 3; ++pr) {
            const int ch0 = j0w + pr * 32 + lrow * 2;
            #pragma unroll
            for (int i = 0; i < 4; ++i) {
                const int t = mt * 16 + lk * 4 + i;
                const int slot = (ch0 >> 3) ^ (t & 7);
                unsigned pv = pk2c(acc[mt][2 * pr][i], acc[mt][2 * pr + 1][i]);
                *(unsigned*)(lds + 16384 + t * 1536 + (slot << 4) + (ch0 & 7) * 2) = pv;
            }
        }
    __syncthreads();                       // barrier 2

    // ---- head-attention (R12-proven): 1 task/thread (tok t, head h, half hf) ----
    {
        const int t  = tid >> 4;
        const int h  = (tid >> 1) & 7;
        const int hf = tid & 1;
        const int tx = t & 7;
        const unsigned char* row = lds + 16384 + t * 1536;
        float q[16];
        #pragma unroll
        for (int jj = 0; jj < 2; ++jj) {
            int slot = (h * 4 + hf * 2 + jj) ^ tx;
            bf16x8 v = *(const bf16x8*)(row + (slot << 4));
            #pragma unroll
            for (int e = 0; e < 8; ++e) q[jj * 8 + e] = bf2f((unsigned short)v[e]);
        }
        float dots[8];
        #pragma unroll
        for (int g = 0; g < 8; ++g) {
            float acc2 = 0.f;
            #pragma unroll
            for (int jj = 0; jj < 2; ++jj) {
                int slot = (32 + g * 4 + hf * 2 + jj) ^ tx;
                bf16x8 v = *(const bf16x8*)(row + (slot << 4));
                #pragma unroll
                for (int e = 0; e < 8; ++e) acc2 += q[jj * 8 + e] * bf2f((unsigned short)v[e]);
            }
            dots[g] = acc2;
        }
        #pragma unroll
        for (int g = 0; g < 8; ++g)
            dots[g] = (dots[g] + __shfl_xor(dots[g], 1, 64)) * SCALE;
        float mx = dots[0];
        #pragma unroll
        for (int g = 1; g < 8; ++g) mx = fmaxf(mx, dots[g]);
        float sum = 0.f;
        #pragma unroll
        for (int g = 0; g < 8; ++g) { dots[g] = __expf(dots[g] - mx); sum += dots[g]; }
        const float inv = 1.f / sum;
        float o[16];
        #pragma unroll
        for (int d = 0; d < 16; ++d) o[d] = 0.f;
        #pragma unroll
        for (int g = 0; g < 8; ++g) {
            const float p = dots[g] * inv;
            #pragma unroll
            for (int jj = 0; jj < 2; ++jj) {
                int slot = (64 + g * 4 + hf * 2 + jj) ^ tx;
                bf16x8 v = *(const bf16x8*)(row + (slot << 4));
                #pragma unroll
                for (int e = 0; e < 8; ++e) o[jj * 8 + e] += p * bf2f((unsigned short)v[e]);
            }
        }
        // mixing fold: out2[win][n'=h*8+r][c'=s*32 + hf*16 + jj*8 + e] (R5-proven)
        const int tok = tb + t;
        const int bb2 = tok >> 14, rem = tok & 16383;
        const int himg = rem >> 7, wimg = rem & 127;
        const int ih = himg >> 3, r = himg & 7;
        const int iw = wimg >> 3, s = wimg & 7;
        const int win = (bb2 << 8) + (ih << 4) + iw;
        unsigned short* dst = o_ws + ((size_t)win * 64 + h * 8 + r) * 256 + s * 32 + hf * 16;
        #pragma unroll
        for (int jj = 0; jj < 2; ++jj) {
            uint4 v = make_uint4(pk2c(o[jj * 8 + 0], o[jj * 8 + 1]), pk2c(o[jj * 8 + 2], o[jj * 8 + 3]),
                                 pk2c(o[jj * 8 + 4], o[jj * 8 + 5]), pk2c(o[jj * 8 + 6], o[jj * 8 + 7]));
            *(uint4*)(dst + jj * 8) = v;
        }
    }
}

// ---- k2: out-projection + bias + output scatter (32KB LDS, two y half-passes)
__global__ __launch_bounds__(512, 6) void outproj_kernel(
        const unsigned short* __restrict__ o_ws, const unsigned short* __restrict__ wo,
        const float* __restrict__ b_out, float* __restrict__ out) {
    __shared__ unsigned char lds[32768];
    const int tid = threadIdx.x;
    const int bid = blockIdx.x;
    const int b  = bid >> 8;
    const int ih = (bid >> 4) & 15;
    const int iw = bid & 15;

    {
        const unsigned char* src = (const unsigned char*)(o_ws + (size_t)bid * 16384);
        #pragma unroll
        for (int it = 0; it < 4; ++it) {
            int q = it * 512 + tid;            // 16-byte chunk id, 2048 total
            int np = q >> 5;                   // row n'
            int slot = (q & 31) ^ (np & 7);
            *(bf16x8*)(lds + np * 512 + (slot << 4)) = *(const bf16x8*)(src + q * 16);
        }
    }
    __syncthreads();

    const int lane = tid & 63;
    const int wave = tid >> 6;
    const int lrow = lane & 15;
    const int lk   = lane >> 4;
    const int j0 = wave * 32;

    f32x4 acc[4][2];
    #pragma unroll
    for (int mt = 0; mt < 4; ++mt)
        #pragma unroll
        for (int nt = 0; nt < 2; ++nt)
            acc[mt][nt] = (f32x4){0.f, 0.f, 0.f, 0.f};
    #pragma unroll
    for (int k = 0; k < 8; ++k) {
        bf16x8 a[4], bb[2];
        #pragma unroll
        for (int mt = 0; mt < 4; ++mt) {
            int t = mt * 16 + lrow;
            int slot = (k * 4 + lk) ^ (t & 7);
            a[mt] = *(const bf16x8*)(lds + t * 512 + (slot << 4));
        }
        #pragma unroll
        for (int nt = 0; nt < 2; ++nt) {
            int j = j0 + nt * 16 + lrow;
            bb[nt] = *(const bf16x8*)((const unsigned char*)wo + (size_t)j * 512 + k * 64 + lk * 16);
        }
        #pragma unroll
        for (int mt = 0; mt < 4; ++mt)
            #pragma unroll
            for (int nt = 0; nt < 2; ++nt)
                acc[mt][nt] = __builtin_amdgcn_mfma_f32_16x16x32_bf16(a[mt], bb[nt], acc[mt][nt], 0, 0, 0);
    }
    float bias[2];
    #pragma unroll
    for (int nt = 0; nt < 2; ++nt) bias[nt] = b_out[j0 + nt * 16 + lrow];
    __syncthreads();   // out2 tile dead; reuse LDS for fp32 y (two 128-col halves)

    const size_t obase = ((size_t)b * 256) * 16384 + (size_t)(iw * 8) * 128 + ih * 8;
    #pragma unroll
    for (int half = 0; half < 2; ++half) {
        if ((wave >> 2) == half) {
            int jl = (wave & 3) * 32;
            #pragma unroll
            for (int mt = 0; mt < 4; ++mt)
                #pragma unroll
                for (int nt = 0; nt < 2; ++nt)
                    #pragma unroll
                    for (int i = 0; i < 4; ++i) {
                        int t = mt * 16 + lk * 4 + i;
                        int el = jl + nt * 16 + lrow;      // 0..127
                        int sl = (el >> 2) ^ (t & 7);
                        *(float*)(lds + t * 512 + (sl << 4) + (el & 3) * 4) = acc[mt][nt][i] + bias[nt];
                    }
        }
        __syncthreads();
        #pragma unroll
        for (int it = 0; it < 2; ++it) {
            int idx = it * 512 + tid;              // 0..1023
            int el = idx >> 3, sp = idx & 7;       // el 0..127
            float vals[8];
            #pragma unroll
            for (int rp = 0; rp < 8; ++rp) {
                int t = rp * 8 + sp;
                int sl = (el >> 2) ^ (t & 7);
                vals[rp] = *(const float*)(lds + t * 512 + (sl << 4) + (el & 3) * 4);
            }
            float* po = out + obase + (size_t)(half * 128 + el) * 16384 + sp * 128;
            *(float4*)po       = make_float4(vals[0], vals[1], vals[2], vals[3]);
            *(float4*)(po + 4) = make_float4(vals[4], vals[5], vals[6], vals[7]);
        }
        __syncthreads();
    }
}

extern "C" void kernel_launch(void* const* d_in, const int* in_sizes, int n_in,
                              void* d_out, int out_size, void* d_ws, size_t ws_size,
                              hipStream_t stream) {
    const float* x     = (const float*)d_in[0];
    const float* w_qkv = (const float*)d_in[1];
    const float* w_out = (const float*)d_in[2];
    const float* b_out = (const float*)d_in[3];
    float* out = (float*)d_out;

    const size_t O_BYTES = 67108864;      // 2048 x 64 x 256 x 2

    unsigned short* o_ws = (unsigned short*)d_ws;
    unsigned short* wq   = (unsigned short*)((char*)d_ws + O_BYTES);
    unsigned short* wo   = wq + 196608;

    wconv_kernel<<<dim3(1024), dim3(256), 0, stream>>>(w_qkv, w_out, wq, wo);
    qkv_attn_fused_kernel<<<dim3(4096), dim3(512), 0, stream>>>(x, wq, o_ws);
    outproj_kernel<<<dim3(2048), dim3(512), 0, stream>>>(o_ws, wo, b_out, out);
}

// Round 15
// 234.735 us; speedup vs baseline: 1.2302x; 1.2244x over previous
//
#include <hip/hip_runtime.h>

#define SCALE 0.17677669529663687f

typedef __attribute__((ext_vector_type(8))) short bf16x8;
typedef __attribute__((ext_vector_type(4))) float f32x4;

__device__ __forceinline__ unsigned short f2bf(float f) {
    unsigned u = __float_as_uint(f);
    u += 0x7FFFu + ((u >> 16) & 1u);   // round-to-nearest-even
    return (unsigned short)(u >> 16);
}
__device__ __forceinline__ float bf2f(unsigned short s) {
    return __uint_as_float(((unsigned)s) << 16);
}
// pack two f32 -> u32 of 2 bf16 (lo = a, hi = b), RNE, pure C (NOTE: inline-asm
// v_cvt_pk_bf16_f32 produced NaNs in round 4 -- do not reintroduce without isolation)
__device__ __forceinline__ unsigned pk2c(float a, float b) {
    return (unsigned)f2bf(a) | ((unsigned)f2bf(b) << 16);
}

// ---------------- weights -> bf16 ----------------
__global__ __launch_bounds__(256) void wconv_kernel(
        const float* __restrict__ w_qkv, const float* __restrict__ w_out,
        unsigned short* __restrict__ wq, unsigned short* __restrict__ wo) {
    int idx = blockIdx.x * 256 + threadIdx.x;
    if (idx < 196608) wq[idx] = f2bf(w_qkv[idx]);
    else if (idx < 262144) wo[idx - 196608] = f2bf(w_out[idx - 196608]);
}

// ---- k1 (primary): fused QKV GEMM + head-attention, M=64 tokens/block.
// 1024 threads (16 waves), 128 KiB DYNAMIC LDS -> 1 block/CU (16 waves = 4/SIMD,
// same wave occupancy as the M=32 version) but HALF the wq L2 streaming
// (2048 blocks x 384 KiB = 0.79 GB) and HALF the barriers per token (2 / 64 tok).
// GEMM: A = x-tile LDS, B = wq L2-stream, wave owns 48 of 768 channels, acc[4][3].
// Attention: R12-proven scalar path, exactly 1 task/thread (64 tok x 8 h x 2 hf).
// LDS: [0,32768) x-tile 64tok x 256ch bf16 swizzled (row 512 B);
//      [32768,131072) qkv 64tok x 768ch bf16 (row 1536 B, chunk-xor swizzle).
__global__ __launch_bounds__(1024, 4) void qkv_attn_fused64_kernel(
        const float* __restrict__ x, const unsigned short* __restrict__ wq,
        unsigned short* __restrict__ o_ws) {
    extern __shared__ unsigned char lds[];
    const int tid = threadIdx.x;
    const int tb  = blockIdx.x << 6;       // 64 consecutive tokens
    const int b   = tb >> 14;
    const float* xb = x + (size_t)b * 4194304 + (tb & 16383);

    // ---- stage x -> LDS bf16 [token][ch] swizzled (R12-proven pattern) ----
    {
        const int tok   = tid & 63;
        const int cbase = (tid >> 6) * 16;
        float f[16];
        #pragma unroll
        for (int e = 0; e < 16; ++e)
            f[e] = xb[(size_t)(cbase + e) * 16384 + tok];
        #pragma unroll
        for (int hlf = 0; hlf < 2; ++hlf) {
            const int c0 = cbase + hlf * 8;
            unsigned u0 = pk2c(f[hlf*8+0], f[hlf*8+1]), u1 = pk2c(f[hlf*8+2], f[hlf*8+3]);
            unsigned u2 = pk2c(f[hlf*8+4], f[hlf*8+5]), u3 = pk2c(f[hlf*8+6], f[hlf*8+7]);
            const int slot = (c0 >> 3) ^ (tok & 7);
            *(uint4*)(lds + tok * 512 + (slot << 4)) = make_uint4(u0, u1, u2, u3);
        }
    }
    __syncthreads();                       // barrier 1

    const int lane = tid & 63;
    const int wave = tid >> 6;             // 0..15
    const int lrow = lane & 15, lk = lane >> 4;
    const int j0w = wave * 48;             // wave's 48-channel slice of 768

    // ---- single-k-loop GEMM over all 768 channels ----
    f32x4 acc[4][3];
    #pragma unroll
    for (int mt = 0; mt < 4; ++mt)
        #pragma unroll
        for (int nt = 0; nt < 3; ++nt)
            acc[mt][nt] = (f32x4){0.f, 0.f, 0.f, 0.f};
    #pragma unroll
    for (int k = 0; k < 8; ++k) {
        bf16x8 a[4], bb[3];
        #pragma unroll
        for (int mt = 0; mt < 4; ++mt) {
            int t = mt * 16 + lrow;
            int slot = (k * 4 + lk) ^ (t & 7);
            a[mt] = *(const bf16x8*)(lds + t * 512 + (slot << 4));
        }
        #pragma unroll
        for (int nt = 0; nt < 3; ++nt) {
            int j = j0w + nt * 16 + lrow;
            bb[nt] = *(const bf16x8*)((const unsigned char*)wq + (size_t)j * 512 + k * 64 + lk * 16);
        }
        #pragma unroll
        for (int mt = 0; mt < 4; ++mt)
            #pragma unroll
            for (int nt = 0; nt < 3; ++nt)
                acc[mt][nt] = __builtin_amdgcn_mfma_f32_16x16x32_bf16(a[mt], bb[nt], acc[mt][nt], 0, 0, 0);
    }
    // ---- bounce D-frags -> qkv LDS (R12-proven layout). col=channel, row=token ----
    #pragma unroll
    for (int mt = 0; mt < 4; ++mt)
        #pragma unroll
        for (int nt = 0; nt < 3; ++nt)
            #pragma unroll
            for (int i = 0; i < 4; ++i) {
                int t = mt * 16 + lk * 4 + i;
                int ch = j0w + nt * 16 + lrow;
                int slot = (ch >> 3) ^ (t & 7);
                *(unsigned short*)(lds + 32768 + t * 1536 + (slot << 4) + (ch & 7) * 2) = f2bf(acc[mt][nt][i]);
            }
    __syncthreads();                       // barrier 2

    // ---- head-attention (R12-proven): 1 task/thread (tok t, head h, half hf) ----
    {
        const int t  = tid >> 4;           // 0..63
        const int h  = (tid >> 1) & 7;
        const int hf = tid & 1;
        const int tx = t & 7;
        const unsigned char* row = lds + 32768 + t * 1536;
        float q[16];
        #pragma unroll
        for (int jj = 0; jj < 2; ++jj) {
            int slot = (h * 4 + hf * 2 + jj) ^ tx;
            bf16x8 v = *(const bf16x8*)(row + (slot << 4));
            #pragma unroll
            for (int e = 0; e < 8; ++e) q[jj * 8 + e] = bf2f((unsigned short)v[e]);
        }
        float dots[8];
        #pragma unroll
        for (int g = 0; g < 8; ++g) {
            float acc2 = 0.f;
            #pragma unroll
            for (int jj = 0; jj < 2; ++jj) {
                int slot = (32 + g * 4 + hf * 2 + jj) ^ tx;
                bf16x8 v = *(const bf16x8*)(row + (slot << 4));
                #pragma unroll
                for (int e = 0; e < 8; ++e) acc2 += q[jj * 8 + e] * bf2f((unsigned short)v[e]);
            }
            dots[g] = acc2;
        }
        #pragma unroll
        for (int g = 0; g < 8; ++g)
            dots[g] = (dots[g] + __shfl_xor(dots[g], 1, 64)) * SCALE;
        float mx = dots[0];
        #pragma unroll
        for (int g = 1; g < 8; ++g) mx = fmaxf(mx, dots[g]);
        float sum = 0.f;
        #pragma unroll
        for (int g = 0; g < 8; ++g) { dots[g] = __expf(dots[g] - mx); sum += dots[g]; }
        const float inv = 1.f / sum;
        float o[16];
        #pragma unroll
        for (int d = 0; d < 16; ++d) o[d] = 0.f;
        #pragma unroll
        for (int g = 0; g < 8; ++g) {
            const float p = dots[g] * inv;
            #pragma unroll
            for (int jj = 0; jj < 2; ++jj) {
                int slot = (64 + g * 4 + hf * 2 + jj) ^ tx;
                bf16x8 v = *(const bf16x8*)(row + (slot << 4));
                #pragma unroll
                for (int e = 0; e < 8; ++e) o[jj * 8 + e] += p * bf2f((unsigned short)v[e]);
            }
        }
        // mixing fold: out2[win][n'=h*8+r][c'=s*32 + hf*16 + jj*8 + e] (R5-proven)
        const int tok = tb + t;
        const int bb2 = tok >> 14, rem = tok & 16383;
        const int himg = rem >> 7, wimg = rem & 127;
        const int ih = himg >> 3, r = himg & 7;
        const int iw = wimg >> 3, s = wimg & 7;
        const int win = (bb2 << 8) + (ih << 4) + iw;
        unsigned short* dst = o_ws + ((size_t)win * 64 + h * 8 + r) * 256 + s * 32 + hf * 16;
        #pragma unroll
        for (int jj = 0; jj < 2; ++jj) {
            uint4 v = make_uint4(pk2c(o[jj * 8 + 0], o[jj * 8 + 1]), pk2c(o[jj * 8 + 2], o[jj * 8 + 3]),
                                 pk2c(o[jj * 8 + 4], o[jj * 8 + 5]), pk2c(o[jj * 8 + 6], o[jj * 8 + 7]));
            *(uint4*)(dst + jj * 8) = v;
        }
    }
}

// ---- k1 (fallback, R12-proven 228us): M=32, 512 thr, 64 KiB static LDS ----
__global__ __launch_bounds__(512, 4) void qkv_attn_fused_kernel(
        const float* __restrict__ x, const unsigned short* __restrict__ wq,
        unsigned short* __restrict__ o_ws) {
    __shared__ unsigned char lds[65536];
    const int tid = threadIdx.x;
    const int tb  = blockIdx.x << 5;
    const int b   = tb >> 14;
    const float* xb = x + (size_t)b * 4194304 + (tb & 16383);

    {
        const int tok   = tid & 31;
        const int cbase = (tid >> 5) * 16;
        float f[16];
        #pragma unroll
        for (int e = 0; e < 16; ++e)
            f[e] = xb[(size_t)(cbase + e) * 16384 + tok];
        #pragma unroll
        for (int hlf = 0; hlf < 2; ++hlf) {
            const int c0 = cbase + hlf * 8;
            unsigned u0 = pk2c(f[hlf*8+0], f[hlf*8+1]), u1 = pk2c(f[hlf*8+2], f[hlf*8+3]);
            unsigned u2 = pk2c(f[hlf*8+4], f[hlf*8+5]), u3 = pk2c(f[hlf*8+6], f[hlf*8+7]);
            const int slot = (c0 >> 3) ^ (tok & 7);
            *(uint4*)(lds + tok * 512 + (slot << 4)) = make_uint4(u0, u1, u2, u3);
        }
    }
    __syncthreads();

    const int lane = tid & 63;
    const int wave = tid >> 6;
    const int lrow = lane & 15, lk = lane >> 4;
    const int j0w = wave * 96;

    f32x4 acc[2][6];
    #pragma unroll
    for (int mt = 0; mt < 2; ++mt)
        #pragma unroll
        for (int nt = 0; nt < 6; ++nt)
            acc[mt][nt] = (f32x4){0.f, 0.f, 0.f, 0.f};
    #pragma unroll
    for (int k = 0; k < 8; ++k) {
        bf16x8 a[2], bb[6];
        #pragma unroll
        for (int mt = 0; mt < 2; ++mt) {
            int t = mt * 16 + lrow;
            int slot = (k * 4 + lk) ^ (t & 7);
            a[mt] = *(const bf16x8*)(lds + t * 512 + (slot << 4));
        }
        #pragma unroll
        for (int nt = 0; nt < 6; ++nt) {
            int j = j0w + nt * 16 + lrow;
            bb[nt] = *(const bf16x8*)((const unsigned char*)wq + (size_t)j * 512 + k * 64 + lk * 16);
        }
        #pragma unroll
        for (int mt = 0; mt < 2; ++mt)
            #pragma unroll
            for (int nt = 0; nt < 6; ++nt)
                acc[mt][nt] = __builtin_amdgcn_mfma_f32_16x16x32_bf16(a[mt], bb[nt], acc[mt][nt], 0, 0, 0);
    }
    #pragma unroll
    for (int mt = 0; mt < 2; ++mt)
        #pragma unroll
        for (int nt = 0; nt < 6; ++nt)
            #pragma unroll
            for (int i = 0; i < 4; ++i) {
                int t = mt * 16 + lk * 4 + i;
                int ch = j0w + nt * 16 + lrow;
                int slot = (ch >> 3) ^ (t & 7);
                *(unsigned short*)(lds + 16384 + t * 1536 + (slot << 4) + (ch & 7) * 2) = f2bf(acc[mt][nt][i]);
            }
    __syncthreads();

    {
        const int t  = tid >> 4;
        const int h  = (tid >> 1) & 7;
        const int hf = tid & 1;
        const int tx = t & 7;
        const unsigned char* row = lds + 16384 + t * 1536;
        float q[16];
        #pragma unroll
        for (int jj = 0; jj < 2; ++jj) {
            int slot = (h * 4 + hf * 2 + jj) ^ tx;
            bf16x8 v = *(const bf16x8*)(row + (slot << 4));
            #pragma unroll
            for (int e = 0; e < 8; ++e) q[jj * 8 + e] = bf2f((unsigned short)v[e]);
        }
        float dots[8];
        #pragma unroll
        for (int g = 0; g < 8; ++g) {
            float acc2 = 0.f;
            #pragma unroll
            for (int jj = 0; jj < 2; ++jj) {
                int slot = (32 + g * 4 + hf * 2 + jj) ^ tx;
                bf16x8 v = *(const bf16x8*)(row + (slot << 4));
                #pragma unroll
                for (int e = 0; e < 8; ++e) acc2 += q[jj * 8 + e] * bf2f((unsigned short)v[e]);
            }
            dots[g] = acc2;
        }
        #pragma unroll
        for (int g = 0; g < 8; ++g)
            dots[g] = (dots[g] + __shfl_xor(dots[g], 1, 64)) * SCALE;
        float mx = dots[0];
        #pragma unroll
        for (int g = 1; g < 8; ++g) mx = fmaxf(mx, dots[g]);
        float sum = 0.f;
        #pragma unroll
        for (int g = 0; g < 8; ++g) { dots[g] = __expf(dots[g] - mx); sum += dots[g]; }
        const float inv = 1.f / sum;
        float o[16];
        #pragma unroll
        for (int d = 0; d < 16; ++d) o[d] = 0.f;
        #pragma unroll
        for (int g = 0; g < 8; ++g) {
            const float p = dots[g] * inv;
            #pragma unroll
            for (int jj = 0; jj < 2; ++jj) {
                int slot = (64 + g * 4 + hf * 2 + jj) ^ tx;
                bf16x8 v = *(const bf16x8*)(row + (slot << 4));
                #pragma unroll
                for (int e = 0; e < 8; ++e) o[jj * 8 + e] += p * bf2f((unsigned short)v[e]);
            }
        }
        const int tok = tb + t;
        const int bb2 = tok >> 14, rem = tok & 16383;
        const int himg = rem >> 7, wimg = rem & 127;
        const int ih = himg >> 3, r = himg & 7;
        const int iw = wimg >> 3, s = wimg & 7;
        const int win = (bb2 << 8) + (ih << 4) + iw;
        unsigned short* dst = o_ws + ((size_t)win * 64 + h * 8 + r) * 256 + s * 32 + hf * 16;
        #pragma unroll
        for (int jj = 0; jj < 2; ++jj) {
            uint4 v = make_uint4(pk2c(o[jj * 8 + 0], o[jj * 8 + 1]), pk2c(o[jj * 8 + 2], o[jj * 8 + 3]),
                                 pk2c(o[jj * 8 + 4], o[jj * 8 + 5]), pk2c(o[jj * 8 + 6], o[jj * 8 + 7]));
            *(uint4*)(dst + jj * 8) = v;
        }
    }
}

// ---- k2: out-projection + bias + output scatter (32KB LDS, two y half-passes)
__global__ __launch_bounds__(512, 6) void outproj_kernel(
        const unsigned short* __restrict__ o_ws, const unsigned short* __restrict__ wo,
        const float* __restrict__ b_out, float* __restrict__ out) {
    __shared__ unsigned char lds[32768];
    const int tid = threadIdx.x;
    const int bid = blockIdx.x;
    const int b  = bid >> 8;
    const int ih = (bid >> 4) & 15;
    const int iw = bid & 15;

    {
        const unsigned char* src = (const unsigned char*)(o_ws + (size_t)bid * 16384);
        #pragma unroll
        for (int it = 0; it < 4; ++it) {
            int q = it * 512 + tid;            // 16-byte chunk id, 2048 total
            int np = q >> 5;                   // row n'
            int slot = (q & 31) ^ (np & 7);
            *(bf16x8*)(lds + np * 512 + (slot << 4)) = *(const bf16x8*)(src + q * 16);
        }
    }
    __syncthreads();

    const int lane = tid & 63;
    const int wave = tid >> 6;
    const int lrow = lane & 15;
    const int lk   = lane >> 4;
    const int j0 = wave * 32;

    f32x4 acc[4][2];
    #pragma unroll
    for (int mt = 0; mt < 4; ++mt)
        #pragma unroll
        for (int nt = 0; nt < 2; ++nt)
            acc[mt][nt] = (f32x4){0.f, 0.f, 0.f, 0.f};
    #pragma unroll
    for (int k = 0; k < 8; ++k) {
        bf16x8 a[4], bb[2];
        #pragma unroll
        for (int mt = 0; mt < 4; ++mt) {
            int t = mt * 16 + lrow;
            int slot = (k * 4 + lk) ^ (t & 7);
            a[mt] = *(const bf16x8*)(lds + t * 512 + (slot << 4));
        }
        #pragma unroll
        for (int nt = 0; nt < 2; ++nt) {
            int j = j0 + nt * 16 + lrow;
            bb[nt] = *(const bf16x8*)((const unsigned char*)wo + (size_t)j * 512 + k * 64 + lk * 16);
        }
        #pragma unroll
        for (int mt = 0; mt < 4; ++mt)
            #pragma unroll
            for (int nt = 0; nt < 2; ++nt)
                acc[mt][nt] = __builtin_amdgcn_mfma_f32_16x16x32_bf16(a[mt], bb[nt], acc[mt][nt], 0, 0, 0);
    }
    float bias[2];
    #pragma unroll
    for (int nt = 0; nt < 2; ++nt) bias[nt] = b_out[j0 + nt * 16 + lrow];
    __syncthreads();   // out2 tile dead; reuse LDS for fp32 y (two 128-col halves)

    const size_t obase = ((size_t)b * 256) * 16384 + (size_t)(iw * 8) * 128 + ih * 8;
    #pragma unroll
    for (int half = 0; half < 2; ++half) {
        if ((wave >> 2) == half) {
            int jl = (wave & 3) * 32;
            #pragma unroll
            for (int mt = 0; mt < 4; ++mt)
                #pragma unroll
                for (int nt = 0; nt < 2; ++nt)
                    #pragma unroll
                    for (int i = 0; i < 4; ++i) {
                        int t = mt * 16 + lk * 4 + i;
                        int el = jl + nt * 16 + lrow;      // 0..127
                        int sl = (el >> 2) ^ (t & 7);
                        *(float*)(lds + t * 512 + (sl << 4) + (el & 3) * 4) = acc[mt][nt][i] + bias[nt];
                    }
        }
        __syncthreads();
        #pragma unroll
        for (int it = 0; it < 2; ++it) {
            int idx = it * 512 + tid;              // 0..1023
            int el = idx >> 3, sp = idx & 7;       // el 0..127
            float vals[8];
            #pragma unroll
            for (int rp = 0; rp < 8; ++rp) {
                int t = rp * 8 + sp;
                int sl = (el >> 2) ^ (t & 7);
                vals[rp] = *(const float*)(lds + t * 512 + (sl << 4) + (el & 3) * 4);
            }
            float* po = out + obase + (size_t)(half * 128 + el) * 16384 + sp * 128;
            *(float4*)po       = make_float4(vals[0], vals[1], vals[2], vals[3]);
            *(float4*)(po + 4) = make_float4(vals[4], vals[5], vals[6], vals[7]);
        }
        __syncthreads();
    }
}

extern "C" void kernel_launch(void* const* d_in, const int* in_sizes, int n_in,
                              void* d_out, int out_size, void* d_ws, size_t ws_size,
                              hipStream_t stream) {
    const float* x     = (const float*)d_in[0];
    const float* w_qkv = (const float*)d_in[1];
    const float* w_out = (const float*)d_in[2];
    const float* b_out = (const float*)d_in[3];
    float* out = (float*)d_out;

    const size_t O_BYTES = 67108864;      // 2048 x 64 x 256 x 2

    unsigned short* o_ws = (unsigned short*)d_ws;
    unsigned short* wq   = (unsigned short*)((char*)d_ws + O_BYTES);
    unsigned short* wo   = wq + 196608;

    wconv_kernel<<<dim3(1024), dim3(256), 0, stream>>>(w_qkv, w_out, wq, wo);

    hipError_t aerr = hipFuncSetAttribute(
        reinterpret_cast<const void*>(qkv_attn_fused64_kernel),
        hipFuncAttributeMaxDynamicSharedMemorySize, 131072);
    if (aerr == hipSuccess) {
        qkv_attn_fused64_kernel<<<dim3(2048), dim3(1024), 131072, stream>>>(x, wq, o_ws);
    } else {
        qkv_attn_fused_kernel<<<dim3(4096), dim3(512), 0, stream>>>(x, wq, o_ws);
    }

    outproj_kernel<<<dim3(2048), dim3(512), 0, stream>>>(o_ws, wo, b_out, out);
}